// Round 1
// baseline (1914.044 us; speedup 1.0000x reference)
//
#include <hip/hip_runtime.h>
#include <math.h>

#define NN 50000
#define EE 800000

// mish(x) = x * tanh(softplus(x)), softplus = log(1+exp(x))
__device__ __forceinline__ float mishf(float v) {
    float e  = __expf(v);
    float sp = (v > 15.0f) ? v : __logf(1.0f + e);
    float e2 = __expf(-2.0f * sp);
    return v * (1.0f - e2) / (1.0f + e2);   // tanh(sp), sp>=0
}

// ---------------- CSR build (dst-sorted edge list) ----------------

__global__ __launch_bounds__(256) void count_k(const int* __restrict__ ei,
                                               int* __restrict__ cnt) {
    int e = blockIdx.x * 256 + threadIdx.x;
    if (e < EE) atomicAdd(&cnt[ei[EE + e]], 1);   // row 1 = dst
}

__global__ __launch_bounds__(1024) void scan_k(const int* __restrict__ cnt,
                                               int* __restrict__ row_off,
                                               int* __restrict__ cur) {
    __shared__ int ps[1024];
    const int t = threadIdx.x;
    const int per = (NN + 1023) / 1024;          // 49
    const int b = t * per;
    const int e = (b + per < NN) ? (b + per) : NN;
    int s = 0;
    for (int i = b; i < e; i++) s += cnt[i];
    ps[t] = s;
    __syncthreads();
    for (int off = 1; off < 1024; off <<= 1) {   // Hillis-Steele inclusive scan
        int v = (t >= off) ? ps[t - off] : 0;
        __syncthreads();
        ps[t] += v;
        __syncthreads();
    }
    int base = (t > 0) ? ps[t - 1] : 0;
    for (int i = b; i < e; i++) {
        row_off[i] = base;
        cur[i] = base;
        base += cnt[i];
    }
    if (t == 1023) row_off[NN] = ps[1023];
}

__global__ __launch_bounds__(256) void scatter_k(const int* __restrict__ ei,
                                                 int* __restrict__ cur,
                                                 int* __restrict__ csr_src) {
    int e = blockIdx.x * 256 + threadIdx.x;
    if (e < EE) {
        int d = ei[EE + e];
        int p = atomicAdd(&cur[d], 1);
        csr_src[p] = ei[e];                       // row 0 = src
    }
}

// ---------------- per-node a0 = xi @ (W1_top - W1_bot) + b1 ----------------

__global__ __launch_bounds__(64)
void a0_64(const float* __restrict__ x, const float* __restrict__ w1,
           const float* __restrict__ b1, float* __restrict__ a0, int nblk) {
    const int lane = threadIdx.x;                 // = channel
    __shared__ __align__(16) float xi[64];
    float wd[64];
#pragma unroll
    for (int k = 0; k < 64; k++) wd[k] = w1[k * 64 + lane] - w1[(64 + k) * 64 + lane];
    const float b = b1[lane];
    for (int n = blockIdx.x; n < NN; n += nblk) {
        xi[lane] = x[(size_t)n * 64 + lane];
        __syncthreads();
        float c0 = 0, c1 = 0, c2 = 0, c3 = 0;
        const float4* xv4 = (const float4*)xi;
#pragma unroll
        for (int k = 0; k < 16; k++) {
            float4 v = xv4[k];
            c0 = fmaf(v.x, wd[4 * k + 0], c0);
            c1 = fmaf(v.y, wd[4 * k + 1], c1);
            c2 = fmaf(v.z, wd[4 * k + 2], c2);
            c3 = fmaf(v.w, wd[4 * k + 3], c3);
        }
        a0[(size_t)n * 64 + lane] = b + ((c0 + c1) + (c2 + c3));
        __syncthreads();                          // xi reused next iteration
    }
}

// ---------------- node-centric fused MLP + segment_max, dout=64 ----------------
// one wave per node; lane = out channel; W1_bot / W2 columns register-resident

__global__ __launch_bounds__(64)
void node_mlp64(const float* __restrict__ x, const float* __restrict__ a0,
                const float* __restrict__ w1, const float* __restrict__ w2,
                const float* __restrict__ b2,
                const int* __restrict__ row_off, const int* __restrict__ csr_src,
                float* __restrict__ y, int nblk) {
    const int lane = threadIdx.x;
    __shared__ __align__(16) float xj[64];
    __shared__ __align__(16) float ub[64];
    float wb[64], wc[64];
#pragma unroll
    for (int k = 0; k < 64; k++) wb[k] = w1[(64 + k) * 64 + lane];
#pragma unroll
    for (int k = 0; k < 64; k++) wc[k] = w2[k * 64 + lane];
    const float bias2 = b2[lane];
    for (int n = blockIdx.x; n < NN; n += nblk) {
        const int beg = row_off[n], end = row_off[n + 1];
        const float a0v = a0[(size_t)n * 64 + lane];
        float m = -INFINITY;
        float xN = 0.0f;
        if (beg < end) { int s0 = csr_src[beg]; xN = x[(size_t)s0 * 64 + lane]; }
        for (int i = beg; i < end; i++) {
            float xc = xN;
            if (i + 1 < end) {                    // prefetch next edge's row
                int s2 = csr_src[i + 1];
                xN = x[(size_t)s2 * 64 + lane];
            }
            xj[lane] = xc;
            __syncthreads();                      // B1: xj visible
            float c0 = 0, c1 = 0, c2 = 0, c3 = 0;
            const float4* xv4 = (const float4*)xj;
#pragma unroll
            for (int k = 0; k < 16; k++) {
                float4 v = xv4[k];
                c0 = fmaf(v.x, wb[4 * k + 0], c0);
                c1 = fmaf(v.y, wb[4 * k + 1], c1);
                c2 = fmaf(v.z, wb[4 * k + 2], c2);
                c3 = fmaf(v.w, wb[4 * k + 3], c3);
            }
            float h1 = a0v + ((c0 + c1) + (c2 + c3));
            ub[lane] = mishf(h1);
            __syncthreads();                      // B2: ub visible (also fences xj reads)
            float d0 = 0, d1 = 0, d2 = 0, d3 = 0;
            const float4* uv4 = (const float4*)ub;
#pragma unroll
            for (int k = 0; k < 16; k++) {
                float4 v = uv4[k];
                d0 = fmaf(v.x, wc[4 * k + 0], d0);
                d1 = fmaf(v.y, wc[4 * k + 1], d1);
                d2 = fmaf(v.z, wc[4 * k + 2], d2);
                d3 = fmaf(v.w, wc[4 * k + 3], d3);
            }
            m = fmaxf(m, bias2 + ((d0 + d1) + (d2 + d3)));
        }
        y[(size_t)n * 64 + lane] = (beg < end) ? m : 0.0f;   // empty segment -> 0
    }
}

// ---------------- BatchNorm (batch stats) ----------------

__global__ __launch_bounds__(256)
void bn_stats(const float* __restrict__ y, float* __restrict__ st) {
    const int tid = threadIdx.x;
    const int ch = tid & 63, grp = tid >> 6;
    float s = 0, q = 0;
    for (int n = blockIdx.x * 4 + grp; n < NN; n += gridDim.x * 4) {
        float v = y[(size_t)n * 64 + ch];
        s += v;
        q = fmaf(v, v, q);
    }
    __shared__ float ls[256], lq[256];
    ls[tid] = s; lq[tid] = q;
    __syncthreads();
    if (tid < 64) {
        s = ls[tid] + ls[tid + 64] + ls[tid + 128] + ls[tid + 192];
        q = lq[tid] + lq[tid + 64] + lq[tid + 128] + lq[tid + 192];
        atomicAdd(&st[ch], s);
        atomicAdd(&st[64 + ch], q);
    }
}

__global__ __launch_bounds__(256)
void bn_apply(float* __restrict__ y, const float* __restrict__ st,
              const float* __restrict__ g, const float* __restrict__ be) {
    int idx = blockIdx.x * 256 + threadIdx.x;
    if (idx >= NN * 64) return;
    int ch = idx & 63;
    float mu  = st[ch] * (1.0f / NN);
    float var = st[64 + ch] * (1.0f / NN) - mu * mu;   // population var (ddof=0)
    float sc  = rsqrtf(var + 1e-5f) * g[ch];
    y[idx] = (y[idx] - mu) * sc + be[ch];
}

// ---------------- final layer, dout=8 ----------------

__global__ __launch_bounds__(256)
void a0_8(const float* __restrict__ x, const float* __restrict__ w1,
          const float* __restrict__ b1, float* __restrict__ a0) {
    __shared__ float wd[512];
    const int tid = threadIdx.x;
    for (int i = tid; i < 512; i += 256) {
        int k = i >> 3, c = i & 7;
        wd[i] = w1[k * 8 + c] - w1[(64 + k) * 8 + c];
    }
    __syncthreads();
    int gid = blockIdx.x * 256 + tid;
    if (gid >= NN * 8) return;
    int n = gid >> 3, c = gid & 7;
    float acc = b1[c];
    const float4* xr = (const float4*)(x + (size_t)n * 64);
#pragma unroll
    for (int k = 0; k < 16; k++) {
        float4 v = xr[k];
        acc = fmaf(v.x, wd[(4 * k + 0) * 8 + c], acc);
        acc = fmaf(v.y, wd[(4 * k + 1) * 8 + c], acc);
        acc = fmaf(v.z, wd[(4 * k + 2) * 8 + c], acc);
        acc = fmaf(v.w, wd[(4 * k + 3) * 8 + c], acc);
    }
    a0[gid] = acc;
}

// one wave per node; 8 edge-slots x 8 channels per wave
__global__ __launch_bounds__(64)
void node_mlp8(const float* __restrict__ x, const float* __restrict__ a0,
               const float* __restrict__ w1, const float* __restrict__ w2,
               const float* __restrict__ b2,
               const int* __restrict__ row_off, const int* __restrict__ csr_src,
               float* __restrict__ out, int nblk) {
    const int lane = threadIdx.x;
    const int slot = lane >> 3, ch = lane & 7;
    __shared__ float ub[64];
    float wb[64];
#pragma unroll
    for (int k = 0; k < 64; k++) wb[k] = w1[(64 + k) * 8 + ch];
    float wc[8];
#pragma unroll
    for (int j = 0; j < 8; j++) wc[j] = w2[j * 8 + ch];
    const float bias2 = b2[ch];
    for (int n = blockIdx.x; n < NN; n += nblk) {
        const int beg = row_off[n], end = row_off[n + 1];
        const float a0v = a0[(size_t)n * 8 + ch];
        float m = -INFINITY;
        for (int i0 = beg; i0 < end; i0 += 8) {
            int e = i0 + slot;
            bool act = e < end;
            int s = csr_src[act ? e : beg];
            float c0 = 0, c1 = 0, c2 = 0, c3 = 0;
            const float4* xr = (const float4*)(x + (size_t)s * 64);
#pragma unroll
            for (int k = 0; k < 16; k++) {
                float4 v = xr[k];
                c0 = fmaf(v.x, wb[4 * k + 0], c0);
                c1 = fmaf(v.y, wb[4 * k + 1], c1);
                c2 = fmaf(v.z, wb[4 * k + 2], c2);
                c3 = fmaf(v.w, wb[4 * k + 3], c3);
            }
            float uu = mishf(a0v + ((c0 + c1) + (c2 + c3)));
            ub[lane] = uu;
            __syncthreads();
            float acc = bias2;
#pragma unroll
            for (int j = 0; j < 8; j++) acc += ub[slot * 8 + j] * wc[j];
            __syncthreads();
            if (act) m = fmaxf(m, acc);
        }
        m = fmaxf(m, __shfl_xor(m, 8));
        m = fmaxf(m, __shfl_xor(m, 16));
        m = fmaxf(m, __shfl_xor(m, 32));
        if (lane < 8) out[(size_t)n * 8 + ch] = (beg < end) ? m : 0.0f;
    }
}

// ---------------- launch ----------------

extern "C" void kernel_launch(void* const* d_in, const int* in_sizes, int n_in,
                              void* d_out, int out_size, void* d_ws, size_t ws_size,
                              hipStream_t stream) {
    const float* x0 = (const float*)d_in[0];
    const int*   ei = (const int*)d_in[1];
    const float* w1[4] = {(const float*)d_in[3],  (const float*)d_in[9],
                          (const float*)d_in[15], (const float*)d_in[21]};
    const float* b1[4] = {(const float*)d_in[4],  (const float*)d_in[10],
                          (const float*)d_in[16], (const float*)d_in[22]};
    const float* w2[4] = {(const float*)d_in[5],  (const float*)d_in[11],
                          (const float*)d_in[17], (const float*)d_in[23]};
    const float* b2[4] = {(const float*)d_in[6],  (const float*)d_in[12],
                          (const float*)d_in[18], (const float*)d_in[24]};
    const float* gg[3] = {(const float*)d_in[7],  (const float*)d_in[13],
                          (const float*)d_in[19]};
    const float* be[3] = {(const float*)d_in[8],  (const float*)d_in[14],
                          (const float*)d_in[20]};

    char* p = (char*)d_ws;
    auto alloc = [&](size_t bytes) -> char* {
        char* r = p;
        p += (bytes + 255) & ~(size_t)255;
        return r;
    };
    int*   cnt     = (int*)alloc((size_t)NN * 4);
    int*   row_off = (int*)alloc((size_t)(NN + 1) * 4);
    int*   cur     = (int*)alloc((size_t)NN * 4);
    int*   csr     = (int*)alloc((size_t)EE * 4);
    float* st      = (float*)alloc(3 * 128 * 4);
    float* a0      = (float*)alloc((size_t)NN * 64 * 4);
    float* a03     = (float*)alloc((size_t)NN * 8 * 4);
    float* bufA    = (float*)alloc((size_t)NN * 64 * 4);
    float* bufB    = (float*)alloc((size_t)NN * 64 * 4);

    hipMemsetAsync(cnt, 0, (size_t)NN * 4, stream);
    hipMemsetAsync(st, 0, 3 * 128 * 4, stream);

    count_k<<<(EE + 255) / 256, 256, 0, stream>>>(ei, cnt);
    scan_k<<<1, 1024, 0, stream>>>(cnt, row_off, cur);
    scatter_k<<<(EE + 255) / 256, 256, 0, stream>>>(ei, cur, csr);

    const int NB = 4096;

    // layer 0: x0 -> bufA
    a0_64<<<NB, 64, 0, stream>>>(x0, w1[0], b1[0], a0, NB);
    node_mlp64<<<NB, 64, 0, stream>>>(x0, a0, w1[0], w2[0], b2[0], row_off, csr, bufA, NB);
    bn_stats<<<128, 256, 0, stream>>>(bufA, st);
    bn_apply<<<(NN * 64 + 255) / 256, 256, 0, stream>>>(bufA, st, gg[0], be[0]);

    // layer 1: bufA -> bufB
    a0_64<<<NB, 64, 0, stream>>>(bufA, w1[1], b1[1], a0, NB);
    node_mlp64<<<NB, 64, 0, stream>>>(bufA, a0, w1[1], w2[1], b2[1], row_off, csr, bufB, NB);
    bn_stats<<<128, 256, 0, stream>>>(bufB, st + 128);
    bn_apply<<<(NN * 64 + 255) / 256, 256, 0, stream>>>(bufB, st + 128, gg[1], be[1]);

    // layer 2: bufB -> bufA
    a0_64<<<NB, 64, 0, stream>>>(bufB, w1[2], b1[2], a0, NB);
    node_mlp64<<<NB, 64, 0, stream>>>(bufB, a0, w1[2], w2[2], b2[2], row_off, csr, bufA, NB);
    bn_stats<<<128, 256, 0, stream>>>(bufA, st + 256);
    bn_apply<<<(NN * 64 + 255) / 256, 256, 0, stream>>>(bufA, st + 256, gg[2], be[2]);

    // layer 3: bufA -> d_out [N,8]
    a0_8<<<(NN * 8 + 255) / 256, 256, 0, stream>>>(bufA, w1[3], b1[3], a03);
    node_mlp8<<<NB, 64, 0, stream>>>(bufA, a03, w1[3], w2[3], b2[3], row_off, csr,
                                     (float*)d_out, NB);
}

// Round 2
// 825.069 us; speedup vs baseline: 2.3199x; 2.3199x over previous
//
#include <hip/hip_runtime.h>
#include <hip/hip_bf16.h>
#include <math.h>

#define NN 50000
#define EE 800000

typedef short s8v __attribute__((ext_vector_type(8)));   // 8 x bf16 (4 VGPRs)
typedef float f4v __attribute__((ext_vector_type(4)));   // MFMA C/D

__device__ __forceinline__ short f2bf(float f) {         // fp32 -> bf16 RNE
    unsigned u = __float_as_uint(f);
    u += 0x7fffu + ((u >> 16) & 1u);
    return (short)(u >> 16);
}

// mish(x) = x * (e^{2x}+2e^x) / (e^{2x}+2e^x+2); guard large x (e^x overflow)
__device__ __forceinline__ float mish_fast(float v) {
    float t = __expf(v);
    float s = t * (t + 2.0f);
    float r = v * s * __builtin_amdgcn_rcpf(s + 2.0f);
    return (v > 15.0f) ? v : r;
}

#define MFMA16(a, b, c) __builtin_amdgcn_mfma_f32_16x16x32_bf16(a, b, c, 0, 0, 0)

// ---------------- CSR build (dst-sorted edge list) ----------------

__global__ __launch_bounds__(256) void count_k(const int* __restrict__ ei,
                                               int* __restrict__ cnt) {
    int e = blockIdx.x * 256 + threadIdx.x;
    if (e < EE) atomicAdd(&cnt[ei[EE + e]], 1);   // row 1 = dst
}

__global__ __launch_bounds__(1024) void scan_k(const int* __restrict__ cnt,
                                               int* __restrict__ row_off,
                                               int* __restrict__ cur) {
    __shared__ int ps[1024];
    const int t = threadIdx.x;
    const int per = (NN + 1023) / 1024;
    const int b = t * per;
    const int e = (b + per < NN) ? (b + per) : NN;
    int s = 0;
    for (int i = b; i < e; i++) s += cnt[i];
    ps[t] = s;
    __syncthreads();
    for (int off = 1; off < 1024; off <<= 1) {
        int v = (t >= off) ? ps[t - off] : 0;
        __syncthreads();
        ps[t] += v;
        __syncthreads();
    }
    int base = (t > 0) ? ps[t - 1] : 0;
    for (int i = b; i < e; i++) {
        row_off[i] = base;
        cur[i] = base;
        base += cnt[i];
    }
    if (t == 1023) row_off[NN] = ps[1023];
}

__global__ __launch_bounds__(256) void scatter_k(const int* __restrict__ ei,
                                                 int* __restrict__ cur,
                                                 int* __restrict__ csr_src) {
    int e = blockIdx.x * 256 + threadIdx.x;
    if (e < EE) {
        int d = ei[EE + e];
        int p = atomicAdd(&cur[d], 1);
        csr_src[p] = ei[e];
    }
}

// ---------------- fp32 -> bf16 buffer convert ----------------

__global__ __launch_bounds__(256)
void cvt_bf16(const float* __restrict__ x, unsigned short* __restrict__ xb, int n) {
    int i = blockIdx.x * 256 + threadIdx.x;
    if (i < n) xb[i] = (unsigned short)f2bf(x[i]);
}

// ---------------- a0 = xi @ (W1_top - W1_bot) + b1   (MFMA, N x 64 GEMM) ------
// NN % 16 == 0 (50000 = 3125*16)

__global__ __launch_bounds__(256)
void a0_mfma(const unsigned short* __restrict__ xb, const float* __restrict__ w1,
             const float* __restrict__ b1, float* __restrict__ a0, int nwt) {
    const int lane = threadIdx.x & 63;
    const int wid = blockIdx.x * 4 + (threadIdx.x >> 6);
    const int i = lane & 15, q = lane >> 4;
    s8v wf[4][2];
#pragma unroll
    for (int nb = 0; nb < 4; nb++)
#pragma unroll
        for (int kh = 0; kh < 2; kh++)
#pragma unroll
            for (int j = 0; j < 8; j++) {
                int k = kh * 32 + q * 8 + j, n = nb * 16 + i;
                wf[nb][kh][j] = f2bf(w1[k * 64 + n] - w1[(64 + k) * 64 + n]);
            }
    float bia[4];
#pragma unroll
    for (int nb = 0; nb < 4; nb++) bia[nb] = b1[nb * 16 + i];

    const int ntiles = NN / 16;
    for (int t = wid; t < ntiles; t += nwt) {
        const int row0 = t * 16;
        const unsigned short* xr = xb + (size_t)(row0 + i) * 64;
        s8v af0 = *(const s8v*)(xr + q * 8);
        s8v af1 = *(const s8v*)(xr + 32 + q * 8);
        const int rowq = row0 + q * 4;
#pragma unroll
        for (int nb = 0; nb < 4; nb++) {
            f4v c = {0.f, 0.f, 0.f, 0.f};
            c = MFMA16(af0, wf[nb][0], c);
            c = MFMA16(af1, wf[nb][1], c);
#pragma unroll
            for (int r = 0; r < 4; r++)
                a0[(size_t)(rowq + r) * 64 + nb * 16 + i] = c[r] + bia[nb];
        }
    }
}

// ------- fused edge-MLP + segment_max per node, MFMA 16-edge tiles -------
// one wave per node; A = Xj[16x64] bf16, B = W1bot / W2 register fragments

__global__ __launch_bounds__(256)
void node_mfma64(const unsigned short* __restrict__ xb, const float* __restrict__ a0,
                 const float* __restrict__ w1, const float* __restrict__ w2,
                 const float* __restrict__ b2,
                 const int* __restrict__ row_off, const int* __restrict__ csr,
                 float* __restrict__ y, int nwt) {
    __shared__ float uld[4][16 * 68];                 // per-wave u tile, stride 68
    const int lane = threadIdx.x & 63;
    const int wv = threadIdx.x >> 6;
    const int wid = blockIdx.x * 4 + wv;
    const int i = lane & 15, q = lane >> 4;
    float* up = &uld[wv][0];

    s8v w1f[4][2], w2f[4][2];
#pragma unroll
    for (int nb = 0; nb < 4; nb++)
#pragma unroll
        for (int kh = 0; kh < 2; kh++)
#pragma unroll
            for (int j = 0; j < 8; j++) {
                int k = kh * 32 + q * 8 + j, n = nb * 16 + i;
                w1f[nb][kh][j] = f2bf(w1[(64 + k) * 64 + n]);
                w2f[nb][kh][j] = f2bf(w2[k * 64 + n]);
            }
    float b2v[4];
#pragma unroll
    for (int nb = 0; nb < 4; nb++) b2v[nb] = b2[nb * 16 + i];

    for (int n = wid; n < NN; n += nwt) {
        const int beg = row_off[n], end = row_off[n + 1];
        if (beg >= end) { y[(size_t)n * 64 + lane] = 0.0f; continue; }
        float a0v[4];
#pragma unroll
        for (int nb = 0; nb < 4; nb++) a0v[nb] = a0[(size_t)n * 64 + nb * 16 + i];
        f4v mx[4];
#pragma unroll
        for (int nb = 0; nb < 4; nb++)
            mx[nb] = (f4v){-INFINITY, -INFINITY, -INFINITY, -INFINITY};

        for (int t = beg; t < end; t += 16) {
            const int cnt = min(16, end - t);
            int e = t + i; if (e >= end) e = end - 1;
            const int src = csr[e];
            const unsigned short* xr = xb + (size_t)src * 64;
            s8v af0 = *(const s8v*)(xr + q * 8);        // A[m=i][k=q*8+j]
            s8v af1 = *(const s8v*)(xr + 32 + q * 8);   // k += 32

            f4v c0 = {0.f, 0.f, 0.f, 0.f}, c1 = c0, c2 = c0, c3 = c0;
            c0 = MFMA16(af0, w1f[0][0], c0); c0 = MFMA16(af1, w1f[0][1], c0);
            c1 = MFMA16(af0, w1f[1][0], c1); c1 = MFMA16(af1, w1f[1][1], c1);
            c2 = MFMA16(af0, w1f[2][0], c2); c2 = MFMA16(af1, w1f[2][1], c2);
            c3 = MFMA16(af0, w1f[3][0], c3); c3 = MFMA16(af1, w1f[3][1], c3);

            // mish -> LDS [row][ch] (row = q*4+r, ch = nb*16+i), word stride 68
            asm volatile("" ::: "memory");              // keep write after prior reads
#pragma unroll
            for (int r = 0; r < 4; r++) {
                const int ro = (q * 4 + r) * 68 + i;
                up[ro +  0] = mish_fast(c0[r] + a0v[0]);
                up[ro + 16] = mish_fast(c1[r] + a0v[1]);
                up[ro + 32] = mish_fast(c2[r] + a0v[2]);
                up[ro + 48] = mish_fast(c3[r] + a0v[3]);
            }
            asm volatile("s_waitcnt lgkmcnt(0)" ::: "memory");  // RAW: writes visible

            // read back in A-layout: u[m=i][k = kh*32 + q*8 + j], convert bf16
            s8v uf[2];
#pragma unroll
            for (int kh = 0; kh < 2; kh++) {
                const f4v* rp = (const f4v*)(up + i * 68 + kh * 32 + q * 8);
                f4v v0 = rp[0], v1 = rp[1];
                s8v uu;
                uu[0] = f2bf(v0[0]); uu[1] = f2bf(v0[1]);
                uu[2] = f2bf(v0[2]); uu[3] = f2bf(v0[3]);
                uu[4] = f2bf(v1[0]); uu[5] = f2bf(v1[1]);
                uu[6] = f2bf(v1[2]); uu[7] = f2bf(v1[3]);
                uf[kh] = uu;
            }
            asm volatile("" ::: "memory");              // reads stay before next writes

#pragma unroll
            for (int nb = 0; nb < 4; nb++) {
                f4v cc = {0.f, 0.f, 0.f, 0.f};
                cc = MFMA16(uf[0], w2f[nb][0], cc);
                cc = MFMA16(uf[1], w2f[nb][1], cc);
#pragma unroll
                for (int r = 0; r < 4; r++) {
                    float v = (q * 4 + r < cnt) ? cc[r] : -INFINITY;
                    mx[nb][r] = fmaxf(mx[nb][r], v);
                }
            }
        }
        // reduce rows: in-lane over 4 regs, then across quads (cols identical)
        float red[4];
#pragma unroll
        for (int nb = 0; nb < 4; nb++) {
            float v = fmaxf(fmaxf(mx[nb][0], mx[nb][1]), fmaxf(mx[nb][2], mx[nb][3]));
            v = fmaxf(v, __shfl_xor(v, 16));
            v = fmaxf(v, __shfl_xor(v, 32));
            red[nb] = v + b2v[nb];
        }
        float out = (q < 2) ? (q == 0 ? red[0] : red[1]) : (q == 2 ? red[2] : red[3]);
        y[(size_t)n * 64 + lane] = out;                 // lane = ch = q*16+i
    }
}

// ---------------- BatchNorm (batch stats) ----------------

__global__ __launch_bounds__(256)
void bn_stats(const float* __restrict__ y, float* __restrict__ st) {
    const int tid = threadIdx.x;
    const int ch = tid & 63, grp = tid >> 6;
    float s = 0, qq = 0;
    for (int n = blockIdx.x * 4 + grp; n < NN; n += gridDim.x * 4) {
        float v = y[(size_t)n * 64 + ch];
        s += v;
        qq = fmaf(v, v, qq);
    }
    __shared__ float ls[256], lq[256];
    ls[tid] = s; lq[tid] = qq;
    __syncthreads();
    if (tid < 64) {
        s  = ls[tid] + ls[tid + 64] + ls[tid + 128] + ls[tid + 192];
        qq = lq[tid] + lq[tid + 64] + lq[tid + 128] + lq[tid + 192];
        atomicAdd(&st[ch], s);
        atomicAdd(&st[64 + ch], qq);
    }
}

// normalize in place (fp32) and emit bf16 copy for the next layer's MFMA
__global__ __launch_bounds__(256)
void bn_apply(float* __restrict__ y, const float* __restrict__ st,
              const float* __restrict__ g, const float* __restrict__ be,
              unsigned short* __restrict__ xbout) {
    int idx = blockIdx.x * 256 + threadIdx.x;
    if (idx >= NN * 64) return;
    int ch = idx & 63;
    float mu  = st[ch] * (1.0f / NN);
    float var = st[64 + ch] * (1.0f / NN) - mu * mu;
    float sc  = rsqrtf(var + 1e-5f) * g[ch];
    float v = (y[idx] - mu) * sc + be[ch];
    y[idx] = v;
    xbout[idx] = (unsigned short)f2bf(v);
}

// ---------------- final layer, dout=8 (fp32 VALU path) ----------------

__global__ __launch_bounds__(256)
void a0_8(const float* __restrict__ x, const float* __restrict__ w1,
          const float* __restrict__ b1, float* __restrict__ a0) {
    __shared__ float wd[512];
    const int tid = threadIdx.x;
    for (int i = tid; i < 512; i += 256) {
        int k = i >> 3, c = i & 7;
        wd[i] = w1[k * 8 + c] - w1[(64 + k) * 8 + c];
    }
    __syncthreads();
    int gid = blockIdx.x * 256 + tid;
    if (gid >= NN * 8) return;
    int n = gid >> 3, c = gid & 7;
    float acc = b1[c];
    const float4* xr = (const float4*)(x + (size_t)n * 64);
#pragma unroll
    for (int k = 0; k < 16; k++) {
        float4 v = xr[k];
        acc = fmaf(v.x, wd[(4 * k + 0) * 8 + c], acc);
        acc = fmaf(v.y, wd[(4 * k + 1) * 8 + c], acc);
        acc = fmaf(v.z, wd[(4 * k + 2) * 8 + c], acc);
        acc = fmaf(v.w, wd[(4 * k + 3) * 8 + c], acc);
    }
    a0[gid] = acc;
}

__global__ __launch_bounds__(64)
void node_mlp8(const float* __restrict__ x, const float* __restrict__ a0,
               const float* __restrict__ w1, const float* __restrict__ w2,
               const float* __restrict__ b2,
               const int* __restrict__ row_off, const int* __restrict__ csr_src,
               float* __restrict__ out, int nblk) {
    const int lane = threadIdx.x;
    const int slot = lane >> 3, ch = lane & 7;
    __shared__ float ub[64];
    float wb[64];
#pragma unroll
    for (int k = 0; k < 64; k++) wb[k] = w1[(64 + k) * 8 + ch];
    float wc[8];
#pragma unroll
    for (int j = 0; j < 8; j++) wc[j] = w2[j * 8 + ch];
    const float bias2 = b2[ch];
    for (int n = blockIdx.x; n < NN; n += nblk) {
        const int beg = row_off[n], end = row_off[n + 1];
        const float a0v = a0[(size_t)n * 8 + ch];
        float m = -INFINITY;
        for (int i0 = beg; i0 < end; i0 += 8) {
            int e = i0 + slot;
            bool act = e < end;
            int s = csr_src[act ? e : beg];
            float c0 = 0, c1 = 0, c2 = 0, c3 = 0;
            const float4* xr = (const float4*)(x + (size_t)s * 64);
#pragma unroll
            for (int k = 0; k < 16; k++) {
                float4 v = xr[k];
                c0 = fmaf(v.x, wb[4 * k + 0], c0);
                c1 = fmaf(v.y, wb[4 * k + 1], c1);
                c2 = fmaf(v.z, wb[4 * k + 2], c2);
                c3 = fmaf(v.w, wb[4 * k + 3], c3);
            }
            float uu = mish_fast(a0v + ((c0 + c1) + (c2 + c3)));
            ub[lane] = uu;
            __syncthreads();
            float acc = bias2;
#pragma unroll
            for (int j = 0; j < 8; j++) acc += ub[slot * 8 + j] * wc[j];
            __syncthreads();
            if (act) m = fmaxf(m, acc);
        }
        m = fmaxf(m, __shfl_xor(m, 8));
        m = fmaxf(m, __shfl_xor(m, 16));
        m = fmaxf(m, __shfl_xor(m, 32));
        if (lane < 8) out[(size_t)n * 8 + ch] = (beg < end) ? m : 0.0f;
    }
}

// ---------------- launch ----------------

extern "C" void kernel_launch(void* const* d_in, const int* in_sizes, int n_in,
                              void* d_out, int out_size, void* d_ws, size_t ws_size,
                              hipStream_t stream) {
    const float* x0 = (const float*)d_in[0];
    const int*   ei = (const int*)d_in[1];
    const float* w1[4] = {(const float*)d_in[3],  (const float*)d_in[9],
                          (const float*)d_in[15], (const float*)d_in[21]};
    const float* b1[4] = {(const float*)d_in[4],  (const float*)d_in[10],
                          (const float*)d_in[16], (const float*)d_in[22]};
    const float* w2[4] = {(const float*)d_in[5],  (const float*)d_in[11],
                          (const float*)d_in[17], (const float*)d_in[23]};
    const float* b2[4] = {(const float*)d_in[6],  (const float*)d_in[12],
                          (const float*)d_in[18], (const float*)d_in[24]};
    const float* gg[3] = {(const float*)d_in[7],  (const float*)d_in[13],
                          (const float*)d_in[19]};
    const float* be[3] = {(const float*)d_in[8],  (const float*)d_in[14],
                          (const float*)d_in[20]};

    char* p = (char*)d_ws;
    auto alloc = [&](size_t bytes) -> char* {
        char* r = p;
        p += (bytes + 255) & ~(size_t)255;
        return r;
    };
    int*   cnt     = (int*)alloc((size_t)NN * 4);
    int*   row_off = (int*)alloc((size_t)(NN + 1) * 4);
    int*   cur     = (int*)alloc((size_t)NN * 4);
    int*   csr     = (int*)alloc((size_t)EE * 4);
    float* st      = (float*)alloc(3 * 128 * 4);
    float* a0      = (float*)alloc((size_t)NN * 64 * 4);   // also reused for a03
    float* bufA    = (float*)alloc((size_t)NN * 64 * 4);
    float* bufB    = (float*)alloc((size_t)NN * 64 * 4);
    unsigned short* xb0 = (unsigned short*)alloc((size_t)NN * 64 * 2); // also xbB
    unsigned short* xbA = (unsigned short*)alloc((size_t)NN * 64 * 2);
    float* a03 = a0;
    unsigned short* xbB = xb0;

    hipMemsetAsync(cnt, 0, (size_t)NN * 4, stream);
    hipMemsetAsync(st, 0, 3 * 128 * 4, stream);

    count_k<<<(EE + 255) / 256, 256, 0, stream>>>(ei, cnt);
    scan_k<<<1, 1024, 0, stream>>>(cnt, row_off, cur);
    scatter_k<<<(EE + 255) / 256, 256, 0, stream>>>(ei, cur, csr);
    cvt_bf16<<<(NN * 64 + 255) / 256, 256, 0, stream>>>(x0, xb0, NN * 64);

    const int NBM = 1024;          // node_mfma64 blocks (4 waves each)
    const int NWT = NBM * 4;
    const int NBA = 256;           // a0_mfma blocks
    const int NWA = NBA * 4;
    const int NB8 = 4096;

    // layer 0: xb0 -> bufA
    a0_mfma<<<NBA, 256, 0, stream>>>(xb0, w1[0], b1[0], a0, NWA);
    node_mfma64<<<NBM, 256, 0, stream>>>(xb0, a0, w1[0], w2[0], b2[0], row_off, csr, bufA, NWT);
    bn_stats<<<128, 256, 0, stream>>>(bufA, st);
    bn_apply<<<(NN * 64 + 255) / 256, 256, 0, stream>>>(bufA, st, gg[0], be[0], xbA);

    // layer 1: xbA -> bufB
    a0_mfma<<<NBA, 256, 0, stream>>>(xbA, w1[1], b1[1], a0, NWA);
    node_mfma64<<<NBM, 256, 0, stream>>>(xbA, a0, w1[1], w2[1], b2[1], row_off, csr, bufB, NWT);
    bn_stats<<<128, 256, 0, stream>>>(bufB, st + 128);
    bn_apply<<<(NN * 64 + 255) / 256, 256, 0, stream>>>(bufB, st + 128, gg[1], be[1], xbB);

    // layer 2: xbB -> bufA  (bufB holds fp32 input for a0? no: a0 reads bf16 xbB)
    a0_mfma<<<NBA, 256, 0, stream>>>(xbB, w1[2], b1[2], a0, NWA);
    node_mfma64<<<NBM, 256, 0, stream>>>(xbB, a0, w1[2], w2[2], b2[2], row_off, csr, bufA, NWT);
    bn_stats<<<128, 256, 0, stream>>>(bufA, st + 256);
    bn_apply<<<(NN * 64 + 255) / 256, 256, 0, stream>>>(bufA, st + 256, gg[2], be[2], xbA);

    // layer 3: bufA (fp32, normalized) -> d_out [N,8]
    a0_8<<<(NN * 8 + 255) / 256, 256, 0, stream>>>(bufA, w1[3], b1[3], a03);
    node_mlp8<<<NB8, 64, 0, stream>>>(bufA, a03, w1[3], w2[3], b2[3], row_off, csr,
                                      (float*)d_out, NB8);
}